// Round 5
// baseline (277.773 us; speedup 1.0000x reference)
//
#include <hip/hip_runtime.h>

#define T_SZ   16384
#define CIN    8
#define COUT   8
#define NPART  16
#define PART_T 1024
#define NCHUNK 32     // chunks per part
#define CHT    32     // timesteps per chunk

struct V3 { float x, y, z; };
__device__ __forceinline__ V3 mkv3(float a, float b, float c) { V3 r; r.x=a; r.y=b; r.z=c; return r; }
__device__ __forceinline__ V3 vadd3(V3 a, V3 b) { return mkv3(a.x+b.x, a.y+b.y, a.z+b.z); }
__device__ __forceinline__ V3 vfma3(V3 acc, float s, V3 w) {
  return mkv3(fmaf(s, w.x, acc.x), fmaf(s, w.y, acc.y), fmaf(s, w.z, acc.z));
}
// A rows: (a0,a1,a2),(0,a1,a2),(0,0,a2)
__device__ __forceinline__ V3 aappf(float a0, float a1, float a2, V3 v) {
  float t2 = a2 * v.z;
  float t1 = fmaf(a1, v.y, t2);
  return mkv3(fmaf(a0, v.x, t1), t1, t2);
}
// combine: E(left|right) = A*E_left + E_right
__device__ __forceinline__ V3 comb(float a0, float a1, float a2, V3 l, V3 r) {
  return vadd3(aappf(a0, a1, a2, l), r);
}

struct Row { float4 lo, hi; };
__device__ __forceinline__ Row ldrow(const float* p) {
  Row r; r.lo = *(const float4*)p; r.hi = *(const float4*)(p + 4); return r;
}
__device__ __forceinline__ Row zrow() { Row r; r.lo = make_float4(0.f,0.f,0.f,0.f); r.hi = r.lo; return r; }
__device__ __forceinline__ float rdot(const Row& r, const float* w) {
  float s = r.lo.x * w[0];
  s = fmaf(r.lo.y, w[1], s); s = fmaf(r.lo.z, w[2], s); s = fmaf(r.lo.w, w[3], s);
  s = fmaf(r.hi.x, w[4], s); s = fmaf(r.hi.y, w[5], s); s = fmaf(r.hi.z, w[6], s);
  s = fmaf(r.hi.w, w[7], s);
  return s;
}

// Shared per-thread preamble: FIR (bv), specials (e0,e1), leaf E5 fold.
// Thread j -> (c = j>>3 in 0..31, o = j&7). Part p, batch b.
struct Pre {
  float bv[CHT];
  V3 e0, e1, E5;
  float a0, a1, a2;
  int o, c, p, b, t0;
};

__device__ __forceinline__ void preamble(
    Pre& P, const float* __restrict__ u, const float* __restrict__ x0,
    const float* __restrict__ ac, const float* __restrict__ bc)
{
  const int j = threadIdx.x;
  P.o = j & 7;  P.c = j >> 3;
  P.p = blockIdx.x & 15;  P.b = blockIdx.x >> 4;
  const int o = P.o;
  P.a0 = ac[0*COUT + o];  P.a1 = ac[1*COUT + o];  P.a2 = ac[2*COUT + o];
  const float a0 = P.a0, a1 = P.a1, a2 = P.a2;

  float w0[8], w1[8], w2[8], w3[8];
#pragma unroll
  for (int i = 0; i < 8; ++i) {
    w0[i] = bc[(0*CIN + i)*COUT + o];
    w1[i] = bc[(1*CIN + i)*COUT + o];
    w2[i] = bc[(2*CIN + i)*COUT + o];
    w3[i] = bc[(3*CIN + i)*COUT + o];
  }

  const float* ub = u + (size_t)P.b * T_SZ * CIN;
  P.t0 = P.p * PART_T + P.c * CHT;
  const int t0 = P.t0;

  {
    Row ra, rb, rc;
    if (t0 == 0) { ra = zrow(); rb = zrow(); rc = zrow(); }
    else {
      ra = ldrow(ub + (size_t)(t0 - 3) * CIN);
      rb = ldrow(ub + (size_t)(t0 - 2) * CIN);
      rc = ldrow(ub + (size_t)(t0 - 1) * CIN);
    }
#pragma unroll
    for (int r = 0; r < CHT; ++r) {
      Row rd = ldrow(ub + (size_t)(t0 + r) * CIN);
      P.bv[r] = rdot(ra, w0) + rdot(rb, w1) + rdot(rc, w2) + rdot(rd, w3);
      ra = rb; rb = rc; rc = rd;
    }
  }

  P.e0 = mkv3(0,0,0);  P.e1 = mkv3(0,0,0);
  if (t0 == 0) {
    float x00 = x0[((size_t)P.b*3 + 0)*COUT + o];
    float x01 = x0[((size_t)P.b*3 + 1)*COUT + o];
    float x02 = x0[((size_t)P.b*3 + 2)*COUT + o];
    float first = P.bv[0] + a2*x00 + a1*x01 + a0*x02;
    P.e0 = mkv3(first, x02, x01);
    P.e1 = mkv3(P.bv[1], P.bv[1], x02);
  }

  // leaf E5 = sum_r A^(5-popc(r)) e_r
  V3 gt[6];
  gt[0] = mkv3(1.f,1.f,1.f);
#pragma unroll
  for (int k = 1; k <= 5; ++k) gt[k] = aappf(a0,a1,a2, gt[k-1]);
  V3 acc;
  if (t0 == 0) {
    V3 q0 = P.e0, q1 = P.e1;
#pragma unroll
    for (int k = 0; k < 5; ++k) q0 = aappf(a0,a1,a2, q0);
#pragma unroll
    for (int k = 0; k < 4; ++k) q1 = aappf(a0,a1,a2, q1);
    acc = vadd3(q0, q1);
#pragma unroll
    for (int r = 2; r < CHT; ++r) acc = vfma3(acc, P.bv[r], gt[5 - __popc(r)]);
  } else {
    acc = mkv3(0,0,0);
#pragma unroll
    for (int r = 0; r < CHT; ++r) acc = vfma3(acc, P.bv[r], gt[5 - __popc(r)]);
  }
  P.E5 = acc;
}

// ---------------- Phase 1: part roots ----------------
__global__ __launch_bounds__(256, 4) void ldtf_p1(
    const float* __restrict__ u, const float* __restrict__ x0,
    const float* __restrict__ ac, const float* __restrict__ bc,
    float* __restrict__ ws)
{
  __shared__ V3 s_E5[NCHUNK*8];
  __shared__ V3 s_tr[30*8];   // l1:0..15 l2:16..23 l3:24..27 l4:28..29

  Pre P;
  preamble(P, u, x0, ac, bc);
  const int j = threadIdx.x, o = P.o;
  const float a0 = P.a0, a1 = P.a1, a2 = P.a2;

  s_E5[P.c*8 + o] = P.E5;
  __syncthreads();
  if (j < 128) { int i = j >> 3; s_tr[i*8+o]      = comb(a0,a1,a2, s_E5[(2*i)*8+o],    s_E5[(2*i+1)*8+o]); }
  __syncthreads();
  if (j < 64)  { int i = j >> 3; s_tr[(16+i)*8+o] = comb(a0,a1,a2, s_tr[(2*i)*8+o],    s_tr[(2*i+1)*8+o]); }
  __syncthreads();
  if (j < 32)  { int i = j >> 3; s_tr[(24+i)*8+o] = comb(a0,a1,a2, s_tr[(16+2*i)*8+o], s_tr[(16+2*i+1)*8+o]); }
  __syncthreads();
  if (j < 16)  { int i = j >> 3; s_tr[(28+i)*8+o] = comb(a0,a1,a2, s_tr[(24+2*i)*8+o], s_tr[(24+2*i+1)*8+o]); }
  __syncthreads();
  if (j < 8) {
    V3 rt = comb(a0,a1,a2, s_tr[28*8+o], s_tr[29*8+o]);
    float* wp = ws + ((size_t)(P.b*NPART + P.p)*8 + o)*3;
    wp[0] = rt.x; wp[1] = rt.y; wp[2] = rt.z;
  }
}

// ---------------- Phase 2: full outputs ----------------
// LDS pool: E5 at [0,768) fl, tr at [768,1488), mt at [1488,2208); then reused
// as staging: 32 blocks x 264 floats = 8448 floats (33792 B).
#define POOL_FLOATS 8448

__global__ __launch_bounds__(256, 2) void ldtf_p2(
    const float* __restrict__ u, const float* __restrict__ x0,
    const float* __restrict__ ac, const float* __restrict__ bc,
    float* __restrict__ out, const float* __restrict__ ws)
{
  __shared__ __align__(16) float s_pool[POOL_FLOATS];
  V3* s_E5 = (V3*)s_pool;          // 256 V3
  V3* s_tr = (V3*)s_pool + 256;    // 240 V3
  V3* s_mt = (V3*)s_pool + 496;    // 240 V3 (uses 30*8)
  float* s_out = s_pool;

  Pre P;
  preamble(P, u, x0, ac, bc);
  const int j = threadIdx.x, o = P.o, c = P.c, p = P.p, b = P.b;
  const float a0 = P.a0, a1 = P.a1, a2 = P.a2;

  s_E5[c*8 + o] = P.E5;
  // cooperative load of the 16 part roots of this b
  if (j < 128) {
    int c2 = j >> 3;
    const float* wp = ws + ((size_t)(b*NPART + c2)*8 + o)*3;
    s_mt[c2*8+o] = mkv3(wp[0], wp[1], wp[2]);
  }
  __syncthreads();

  // in-part up-sweep + mini-tree (interleaved across thread ranges)
  if (j < 128) { int i = j >> 3; s_tr[i*8+o]      = comb(a0,a1,a2, s_E5[(2*i)*8+o],    s_E5[(2*i+1)*8+o]); }
  else         { int i = (j-128) >> 3; if (i < 8) s_mt[(16+i)*8+o] = comb(a0,a1,a2, s_mt[(2*i)*8+o], s_mt[(2*i+1)*8+o]); }
  __syncthreads();
  if (j < 64)  { int i = j >> 3; s_tr[(16+i)*8+o] = comb(a0,a1,a2, s_tr[(2*i)*8+o],    s_tr[(2*i+1)*8+o]); }
  else if (j >= 128) { int i = (j-128) >> 3; if (i < 4) s_mt[(24+i)*8+o] = comb(a0,a1,a2, s_mt[(16+2*i)*8+o], s_mt[(16+2*i+1)*8+o]); }
  __syncthreads();
  if (j < 32)  { int i = j >> 3; s_tr[(24+i)*8+o] = comb(a0,a1,a2, s_tr[(16+2*i)*8+o], s_tr[(16+2*i+1)*8+o]); }
  else if (j >= 128) { int i = (j-128) >> 3; if (i < 2) s_mt[(28+i)*8+o] = comb(a0,a1,a2, s_mt[(24+2*i)*8+o], s_mt[(24+2*i+1)*8+o]); }
  __syncthreads();
  if (j < 16)  { int i = j >> 3; s_tr[(28+i)*8+o] = comb(a0,a1,a2, s_tr[(24+2*i)*8+o], s_tr[(24+2*i+1)*8+o]); }
  __syncthreads();

  // ---- sigma = rho(t0 - 1): Fenwick fold over p-bits (mini-tree) then c-bits ----
  V3 sig = mkv3(0,0,0);
  if ((p >> 3) & 1) sig = comb(a0,a1,a2, sig, s_mt[(28 + (p>>3) - 1)*8 + o]);
  if ((p >> 2) & 1) sig = comb(a0,a1,a2, sig, s_mt[(24 + (p>>2) - 1)*8 + o]);
  if ((p >> 1) & 1) sig = comb(a0,a1,a2, sig, s_mt[(16 + (p>>1) - 1)*8 + o]);
  if (p & 1)        sig = comb(a0,a1,a2, sig, s_mt[(p - 1)*8 + o]);
  if ((c >> 4) & 1) sig = comb(a0,a1,a2, sig, s_tr[(28 + (c>>4) - 1)*8 + o]);
  if ((c >> 3) & 1) sig = comb(a0,a1,a2, sig, s_tr[(24 + (c>>3) - 1)*8 + o]);
  if ((c >> 2) & 1) sig = comb(a0,a1,a2, sig, s_tr[(16 + (c>>2) - 1)*8 + o]);
  if ((c >> 1) & 1) sig = comb(a0,a1,a2, sig, s_tr[((c>>1) - 1)*8 + o]);
  if (c & 1)        sig = comb(a0,a1,a2, sig, s_E5[(c - 1)*8 + o]);

  // ---- tau = rho(end of part p) = prefix fold over q = p+1 parts ----
  V3 tau;
  {
    int q = p + 1;
    if (q == 16) tau = comb(a0,a1,a2, s_mt[28*8+o], s_mt[29*8+o]);
    else {
      tau = mkv3(0,0,0);
      if ((q >> 3) & 1) tau = comb(a0,a1,a2, tau, s_mt[(28 + (q>>3) - 1)*8 + o]);
      if ((q >> 2) & 1) tau = comb(a0,a1,a2, tau, s_mt[(24 + (q>>2) - 1)*8 + o]);
      if ((q >> 1) & 1) tau = comb(a0,a1,a2, tau, s_mt[(16 + (q>>1) - 1)*8 + o]);
      if (q & 1)        tau = comb(a0,a1,a2, tau, s_mt[(q - 1)*8 + o]);
    }
  }
  __syncthreads();   // trees dead; s_pool becomes staging

  // stage sigma (local pos c*32 - 1) and tau (local pos 1023)
  if (c >= 1) s_out[(c - 1)*264 + 31*8 + o] = sig.x;
  if (c == NCHUNK - 1) s_out[31*264 + 31*8 + o] = tau.x;

  // ---- local binary-counter scan: stage pos c*32 + r, r = 0..30 ----
  {
    V3 st[5];
#pragma unroll
    for (int r = 0; r < CHT - 1; ++r) {
      V3 v = mkv3(P.bv[r], P.bv[r], P.bv[r]);
      if (P.t0 == 0) { if (r == 0) v = P.e0; if (r == 1) v = P.e1; }
      if (r & 1)          v = comb(a0,a1,a2, st[0], v);
      if ((r & 3) == 3)   v = comb(a0,a1,a2, st[1], v);
      if ((r & 7) == 7)   v = comb(a0,a1,a2, st[2], v);
      if ((r & 15) == 15) v = comb(a0,a1,a2, st[3], v);
      const int lvl = (r & 1) ? (((r & 3) == 3) ? (((r & 7) == 7) ? (((r & 15) == 15) ? 4 : 3) : 2) : 1) : 0;
      st[lvl] = v;
      const int i = r + 1;
      V3 acc = sig;
      if (i & 16) acc = comb(a0,a1,a2, acc, st[4]);
      if (i & 8)  acc = comb(a0,a1,a2, acc, st[3]);
      if (i & 4)  acc = comb(a0,a1,a2, acc, st[2]);
      if (i & 2)  acc = comb(a0,a1,a2, acc, st[1]);
      if (i & 1)  acc = comb(a0,a1,a2, acc, st[0]);
      s_out[c*264 + r*8 + o] = acc.x;
    }
  }
  __syncthreads();

  // ---- coalesced copy-out: 8 iters x 256 threads x float4 ----
  float* og = out + ((size_t)b * T_SZ + (size_t)p * PART_T) * COUT;
#pragma unroll
  for (int it = 0; it < 8; ++it) {
    int f = (it * 256 + j) * 4;
    float4 v = *(const float4*)&s_out[(f >> 8) * 264 + (f & 255)];
    *(float4*)&og[f] = v;
  }
}

extern "C" void kernel_launch(void* const* d_in, const int* in_sizes, int n_in,
                              void* d_out, int out_size, void* d_ws, size_t ws_size,
                              hipStream_t stream) {
  const float* u  = (const float*)d_in[0];
  const float* x0 = (const float*)d_in[1];
  const float* ac = (const float*)d_in[2];
  const float* bc = (const float*)d_in[3];
  float* outp = (float*)d_out;
  float* wsp  = (float*)d_ws;
  (void)ws_size; (void)in_sizes; (void)n_in; (void)out_size;
  const int grid = 64 * NPART;
  ldtf_p1<<<dim3(grid), dim3(256), 0, stream>>>(u, x0, ac, bc, wsp);
  ldtf_p2<<<dim3(grid), dim3(256), 0, stream>>>(u, x0, ac, bc, outp, wsp);
}

// Round 6
// 133.348 us; speedup vs baseline: 2.0831x; 2.0831x over previous
//
#include <hip/hip_runtime.h>

#define T_SZ   16384
#define CIN    8
#define COUT   8
#define NPART  16
#define PART_T 1024
#define NCHUNK 32     // chunks per part
#define CHT    32     // timesteps per chunk

struct V3 { float x, y, z; };
__device__ __forceinline__ V3 mkv3(float a, float b, float c) { V3 r; r.x=a; r.y=b; r.z=c; return r; }
__device__ __forceinline__ V3 vadd3(V3 a, V3 b) { return mkv3(a.x+b.x, a.y+b.y, a.z+b.z); }
__device__ __forceinline__ V3 vfma3(V3 acc, float s, V3 w) {
  return mkv3(fmaf(s, w.x, acc.x), fmaf(s, w.y, acc.y), fmaf(s, w.z, acc.z));
}
// A rows: (a0,a1,a2),(0,a1,a2),(0,0,a2)
__device__ __forceinline__ V3 aappf(float a0, float a1, float a2, V3 v) {
  float t2 = a2 * v.z;
  float t1 = fmaf(a1, v.y, t2);
  return mkv3(fmaf(a0, v.x, t1), t1, t2);
}
// combine: E(left|right) = A*E_left + E_right
__device__ __forceinline__ V3 comb(float a0, float a1, float a2, V3 l, V3 r) {
  return vadd3(aappf(a0, a1, a2, l), r);
}

struct Row { float4 lo, hi; };
__device__ __forceinline__ Row ldrow(const float* p) {
  Row r; r.lo = *(const float4*)p; r.hi = *(const float4*)(p + 4); return r;
}
__device__ __forceinline__ Row zrow() { Row r; r.lo = make_float4(0.f,0.f,0.f,0.f); r.hi = r.lo; return r; }
__device__ __forceinline__ float rdot(const Row& r, const float* w) {
  float s = r.lo.x * w[0];
  s = fmaf(r.lo.y, w[1], s); s = fmaf(r.lo.z, w[2], s); s = fmaf(r.lo.w, w[3], s);
  s = fmaf(r.hi.x, w[4], s); s = fmaf(r.hi.y, w[5], s); s = fmaf(r.hi.z, w[6], s);
  s = fmaf(r.hi.w, w[7], s);
  return s;
}

// Shared per-thread preamble: FIR (bv), specials (e0,e1), leaf E5 fold.
// Thread j -> (c = j>>3 in 0..31, o = j&7). Part p, batch b.
struct Pre {
  float bv[CHT];
  V3 e0, e1, E5;
  float a0, a1, a2;
  int o, c, p, b, t0;
};

__device__ __forceinline__ void preamble(
    Pre& P, const float* __restrict__ u, const float* __restrict__ x0,
    const float* __restrict__ ac, const float* __restrict__ bc)
{
  const int j = threadIdx.x;
  P.o = j & 7;  P.c = j >> 3;
  P.p = blockIdx.x & 15;  P.b = blockIdx.x >> 4;
  const int o = P.o;
  P.a0 = ac[0*COUT + o];  P.a1 = ac[1*COUT + o];  P.a2 = ac[2*COUT + o];
  const float a0 = P.a0, a1 = P.a1, a2 = P.a2;

  float w0[8], w1[8], w2[8], w3[8];
#pragma unroll
  for (int i = 0; i < 8; ++i) {
    w0[i] = bc[(0*CIN + i)*COUT + o];
    w1[i] = bc[(1*CIN + i)*COUT + o];
    w2[i] = bc[(2*CIN + i)*COUT + o];
    w3[i] = bc[(3*CIN + i)*COUT + o];
  }

  const float* ub = u + (size_t)P.b * T_SZ * CIN;
  P.t0 = P.p * PART_T + P.c * CHT;
  const int t0 = P.t0;

  {
    Row ra, rb, rc;
    if (t0 == 0) { ra = zrow(); rb = zrow(); rc = zrow(); }
    else {
      ra = ldrow(ub + (size_t)(t0 - 3) * CIN);
      rb = ldrow(ub + (size_t)(t0 - 2) * CIN);
      rc = ldrow(ub + (size_t)(t0 - 1) * CIN);
    }
#pragma unroll
    for (int r = 0; r < CHT; ++r) {
      Row rd = ldrow(ub + (size_t)(t0 + r) * CIN);
      P.bv[r] = rdot(ra, w0) + rdot(rb, w1) + rdot(rc, w2) + rdot(rd, w3);
      ra = rb; rb = rc; rc = rd;
    }
  }

  P.e0 = mkv3(0,0,0);  P.e1 = mkv3(0,0,0);
  if (t0 == 0) {
    float x00 = x0[((size_t)P.b*3 + 0)*COUT + o];
    float x01 = x0[((size_t)P.b*3 + 1)*COUT + o];
    float x02 = x0[((size_t)P.b*3 + 2)*COUT + o];
    float first = P.bv[0] + a2*x00 + a1*x01 + a0*x02;
    P.e0 = mkv3(first, x02, x01);
    P.e1 = mkv3(P.bv[1], P.bv[1], x02);
  }

  // leaf E5 = sum_r A^(5-popc(r)) e_r
  V3 gt[6];
  gt[0] = mkv3(1.f,1.f,1.f);
#pragma unroll
  for (int k = 1; k <= 5; ++k) gt[k] = aappf(a0,a1,a2, gt[k-1]);
  V3 acc;
  if (t0 == 0) {
    V3 q0 = P.e0, q1 = P.e1;
#pragma unroll
    for (int k = 0; k < 5; ++k) q0 = aappf(a0,a1,a2, q0);
#pragma unroll
    for (int k = 0; k < 4; ++k) q1 = aappf(a0,a1,a2, q1);
    acc = vadd3(q0, q1);
#pragma unroll
    for (int r = 2; r < CHT; ++r) acc = vfma3(acc, P.bv[r], gt[5 - __popc(r)]);
  } else {
    acc = mkv3(0,0,0);
#pragma unroll
    for (int r = 0; r < CHT; ++r) acc = vfma3(acc, P.bv[r], gt[5 - __popc(r)]);
  }
  P.E5 = acc;
}

// ---------------- Phase 1: part roots ----------------
// NOTE: no min-occupancy arg — rounds 2..5 used __launch_bounds__(…,4) which
// capped VGPRs at 64 and forced ~900 B/thread scratch spill traffic
// (WRITE_SIZE 232 MB vs 0.4 MB actual output, dur == scratch bytes / 2.5 TB/s).
__global__ __launch_bounds__(256) void ldtf_p1(
    const float* __restrict__ u, const float* __restrict__ x0,
    const float* __restrict__ ac, const float* __restrict__ bc,
    float* __restrict__ ws)
{
  __shared__ V3 s_E5[NCHUNK*8];
  __shared__ V3 s_tr[30*8];   // l1:0..15 l2:16..23 l3:24..27 l4:28..29

  Pre P;
  preamble(P, u, x0, ac, bc);
  const int j = threadIdx.x, o = P.o;
  const float a0 = P.a0, a1 = P.a1, a2 = P.a2;

  s_E5[P.c*8 + o] = P.E5;
  __syncthreads();
  if (j < 128) { int i = j >> 3; s_tr[i*8+o]      = comb(a0,a1,a2, s_E5[(2*i)*8+o],    s_E5[(2*i+1)*8+o]); }
  __syncthreads();
  if (j < 64)  { int i = j >> 3; s_tr[(16+i)*8+o] = comb(a0,a1,a2, s_tr[(2*i)*8+o],    s_tr[(2*i+1)*8+o]); }
  __syncthreads();
  if (j < 32)  { int i = j >> 3; s_tr[(24+i)*8+o] = comb(a0,a1,a2, s_tr[(16+2*i)*8+o], s_tr[(16+2*i+1)*8+o]); }
  __syncthreads();
  if (j < 16)  { int i = j >> 3; s_tr[(28+i)*8+o] = comb(a0,a1,a2, s_tr[(24+2*i)*8+o], s_tr[(24+2*i+1)*8+o]); }
  __syncthreads();
  if (j < 8) {
    V3 rt = comb(a0,a1,a2, s_tr[28*8+o], s_tr[29*8+o]);
    float* wp = ws + ((size_t)(P.b*NPART + P.p)*8 + o)*3;
    wp[0] = rt.x; wp[1] = rt.y; wp[2] = rt.z;
  }
}

// ---------------- Phase 2: full outputs ----------------
// LDS pool: E5 at [0,768) fl, tr at [768,1488), mt at [1488,2208); then reused
// as staging: 32 blocks x 264 floats = 8448 floats (33792 B).
#define POOL_FLOATS 8448

__global__ __launch_bounds__(256) void ldtf_p2(
    const float* __restrict__ u, const float* __restrict__ x0,
    const float* __restrict__ ac, const float* __restrict__ bc,
    float* __restrict__ out, const float* __restrict__ ws)
{
  __shared__ __align__(16) float s_pool[POOL_FLOATS];
  V3* s_E5 = (V3*)s_pool;          // 256 V3
  V3* s_tr = (V3*)s_pool + 256;    // 240 V3
  V3* s_mt = (V3*)s_pool + 496;    // 240 V3 (uses 30*8)
  float* s_out = s_pool;

  Pre P;
  preamble(P, u, x0, ac, bc);
  const int j = threadIdx.x, o = P.o, c = P.c, p = P.p, b = P.b;
  const float a0 = P.a0, a1 = P.a1, a2 = P.a2;

  s_E5[c*8 + o] = P.E5;
  // cooperative load of the 16 part roots of this b
  if (j < 128) {
    int c2 = j >> 3;
    const float* wp = ws + ((size_t)(b*NPART + c2)*8 + o)*3;
    s_mt[c2*8+o] = mkv3(wp[0], wp[1], wp[2]);
  }
  __syncthreads();

  // in-part up-sweep + mini-tree (interleaved across thread ranges)
  if (j < 128) { int i = j >> 3; s_tr[i*8+o]      = comb(a0,a1,a2, s_E5[(2*i)*8+o],    s_E5[(2*i+1)*8+o]); }
  else         { int i = (j-128) >> 3; if (i < 8) s_mt[(16+i)*8+o] = comb(a0,a1,a2, s_mt[(2*i)*8+o], s_mt[(2*i+1)*8+o]); }
  __syncthreads();
  if (j < 64)  { int i = j >> 3; s_tr[(16+i)*8+o] = comb(a0,a1,a2, s_tr[(2*i)*8+o],    s_tr[(2*i+1)*8+o]); }
  else if (j >= 128) { int i = (j-128) >> 3; if (i < 4) s_mt[(24+i)*8+o] = comb(a0,a1,a2, s_mt[(16+2*i)*8+o], s_mt[(16+2*i+1)*8+o]); }
  __syncthreads();
  if (j < 32)  { int i = j >> 3; s_tr[(24+i)*8+o] = comb(a0,a1,a2, s_tr[(16+2*i)*8+o], s_tr[(16+2*i+1)*8+o]); }
  else if (j >= 128) { int i = (j-128) >> 3; if (i < 2) s_mt[(28+i)*8+o] = comb(a0,a1,a2, s_mt[(24+2*i)*8+o], s_mt[(24+2*i+1)*8+o]); }
  __syncthreads();
  if (j < 16)  { int i = j >> 3; s_tr[(28+i)*8+o] = comb(a0,a1,a2, s_tr[(24+2*i)*8+o], s_tr[(24+2*i+1)*8+o]); }
  __syncthreads();

  // ---- sigma = rho(t0 - 1): Fenwick fold over p-bits (mini-tree) then c-bits ----
  V3 sig = mkv3(0,0,0);
  if ((p >> 3) & 1) sig = comb(a0,a1,a2, sig, s_mt[(28 + (p>>3) - 1)*8 + o]);
  if ((p >> 2) & 1) sig = comb(a0,a1,a2, sig, s_mt[(24 + (p>>2) - 1)*8 + o]);
  if ((p >> 1) & 1) sig = comb(a0,a1,a2, sig, s_mt[(16 + (p>>1) - 1)*8 + o]);
  if (p & 1)        sig = comb(a0,a1,a2, sig, s_mt[(p - 1)*8 + o]);
  if ((c >> 4) & 1) sig = comb(a0,a1,a2, sig, s_tr[(28 + (c>>4) - 1)*8 + o]);
  if ((c >> 3) & 1) sig = comb(a0,a1,a2, sig, s_tr[(24 + (c>>3) - 1)*8 + o]);
  if ((c >> 2) & 1) sig = comb(a0,a1,a2, sig, s_tr[(16 + (c>>2) - 1)*8 + o]);
  if ((c >> 1) & 1) sig = comb(a0,a1,a2, sig, s_tr[((c>>1) - 1)*8 + o]);
  if (c & 1)        sig = comb(a0,a1,a2, sig, s_E5[(c - 1)*8 + o]);

  // ---- tau = rho(end of part p) = prefix fold over q = p+1 parts ----
  V3 tau;
  {
    int q = p + 1;
    if (q == 16) tau = comb(a0,a1,a2, s_mt[28*8+o], s_mt[29*8+o]);
    else {
      tau = mkv3(0,0,0);
      if ((q >> 3) & 1) tau = comb(a0,a1,a2, tau, s_mt[(28 + (q>>3) - 1)*8 + o]);
      if ((q >> 2) & 1) tau = comb(a0,a1,a2, tau, s_mt[(24 + (q>>2) - 1)*8 + o]);
      if ((q >> 1) & 1) tau = comb(a0,a1,a2, tau, s_mt[(16 + (q>>1) - 1)*8 + o]);
      if (q & 1)        tau = comb(a0,a1,a2, tau, s_mt[(q - 1)*8 + o]);
    }
  }
  __syncthreads();   // trees dead; s_pool becomes staging

  // stage sigma (local pos c*32 - 1) and tau (local pos 1023)
  if (c >= 1) s_out[(c - 1)*264 + 31*8 + o] = sig.x;
  if (c == NCHUNK - 1) s_out[31*264 + 31*8 + o] = tau.x;

  // ---- local binary-counter scan: stage pos c*32 + r, r = 0..30 ----
  {
    V3 st[5];
#pragma unroll
    for (int r = 0; r < CHT - 1; ++r) {
      V3 v = mkv3(P.bv[r], P.bv[r], P.bv[r]);
      if (P.t0 == 0) { if (r == 0) v = P.e0; if (r == 1) v = P.e1; }
      if (r & 1)          v = comb(a0,a1,a2, st[0], v);
      if ((r & 3) == 3)   v = comb(a0,a1,a2, st[1], v);
      if ((r & 7) == 7)   v = comb(a0,a1,a2, st[2], v);
      if ((r & 15) == 15) v = comb(a0,a1,a2, st[3], v);
      const int lvl = (r & 1) ? (((r & 3) == 3) ? (((r & 7) == 7) ? (((r & 15) == 15) ? 4 : 3) : 2) : 1) : 0;
      st[lvl] = v;
      const int i = r + 1;
      V3 acc = sig;
      if (i & 16) acc = comb(a0,a1,a2, acc, st[4]);
      if (i & 8)  acc = comb(a0,a1,a2, acc, st[3]);
      if (i & 4)  acc = comb(a0,a1,a2, acc, st[2]);
      if (i & 2)  acc = comb(a0,a1,a2, acc, st[1]);
      if (i & 1)  acc = comb(a0,a1,a2, acc, st[0]);
      s_out[c*264 + r*8 + o] = acc.x;
    }
  }
  __syncthreads();

  // ---- coalesced copy-out: 8 iters x 256 threads x float4 ----
  float* og = out + ((size_t)b * T_SZ + (size_t)p * PART_T) * COUT;
#pragma unroll
  for (int it = 0; it < 8; ++it) {
    int f = (it * 256 + j) * 4;
    float4 v = *(const float4*)&s_out[(f >> 8) * 264 + (f & 255)];
    *(float4*)&og[f] = v;
  }
}

extern "C" void kernel_launch(void* const* d_in, const int* in_sizes, int n_in,
                              void* d_out, int out_size, void* d_ws, size_t ws_size,
                              hipStream_t stream) {
  const float* u  = (const float*)d_in[0];
  const float* x0 = (const float*)d_in[1];
  const float* ac = (const float*)d_in[2];
  const float* bc = (const float*)d_in[3];
  float* outp = (float*)d_out;
  float* wsp  = (float*)d_ws;
  (void)ws_size; (void)in_sizes; (void)n_in; (void)out_size;
  const int grid = 64 * NPART;
  ldtf_p1<<<dim3(grid), dim3(256), 0, stream>>>(u, x0, ac, bc, wsp);
  ldtf_p2<<<dim3(grid), dim3(256), 0, stream>>>(u, x0, ac, bc, outp, wsp);
}